// Round 17
// baseline (632.840 us; speedup 1.0000x reference)
//
#include <hip/hip_runtime.h>

// ---------------------------------------------------------------------------
// OT_Attn: unbalanced Sinkhorn on MI355X.
// R22: final visibility bisection step: SPEC_TICKS 70 -> 65. Bracket state:
// 60 fails badly (R12: snapshot ~0.9us post-publish misses systematically),
// 70 clean (R21: sinkhorn 517.5, FETCH flat). At 65 the snapshot lands
// ~0.95-1.0us post-publish, at the measured store-visibility edge; the
// one-shot masked re-read (stale entries only, owning threads, post-window)
// absorbs marginal stragglers, root-gated retry is the terminal backstop.
// Clean -> -10us, bracket [60,65] = effective floor. Marginal -> bounded,
// revert to 70 next round. Correctness unchanged (sign-parity tag-verified
// everywhere). Everything else byte-identical to R21 (sinkhorn 517.5):
// eo2 conflict-free us/vs layout (conflicts 19.7M->4.9M), 512-thread
// sinkhorn, LDS-staged GEMM, sign-parity 4B exchange, R10-proven skeleton:
// publish -> raw barrier -> blkflag -> [agg bid0/1 scans 256 flags -> 32
// line-spaced root replicas] -> spin to deadline -> burst read -> masked
// re-read -> (rare) root-gated retry. Never read during the publish window.
// ONLY validated relaxed AGENT __hip_atomic ops touch shared sync state.
// ---------------------------------------------------------------------------

#define NROWS 4096
#define MCOLS 2048
#define NITER 100
#define NBLK  256    // 1 block/CU (LDS-bound), grid == CU count -> co-resident
#define SPEC_TICKS 65ull   // 0.65 us at 100 MHz realtime clock (bisect probe)

using short8  = __attribute__((ext_vector_type(8))) short;
using floatx4 = __attribute__((ext_vector_type(4))) float;

__device__ __forceinline__ float bf2f(unsigned short u) {
  return __uint_as_float(((unsigned)u) << 16);
}
__device__ __forceinline__ unsigned short f2bf(float f) {  // RNE
  unsigned u = __float_as_uint(f);
  u += 0x7fffu + ((u >> 16) & 1u);
  return (unsigned short)(u >> 16);
}
__device__ __forceinline__ float powfi(float x, float fi) {
  return __expf(fi * __logf(x));
}
// sign-bit-parity pack: val > 0 strictly -> sign bit is free
__device__ __forceinline__ unsigned packsp(float v, unsigned parity) {
  return __float_as_uint(v) | (parity << 31);
}
__device__ __forceinline__ unsigned aload(const unsigned* p) {
  return __hip_atomic_load(p, __ATOMIC_RELAXED, __HIP_MEMORY_SCOPE_AGENT);
}
__device__ __forceinline__ void astore(unsigned* p, unsigned v) {
  __hip_atomic_store(p, v, __ATOMIC_RELAXED, __HIP_MEMORY_SCOPE_AGENT);
}
// async global->LDS, 16B per lane (dest = wave-uniform base + lane*16)
__device__ __forceinline__ void gload_lds16(const unsigned short* gsrc, unsigned short* ldst) {
  __builtin_amdgcn_global_load_lds(
      (const __attribute__((address_space(1))) void*)gsrc,
      (__attribute__((address_space(3))) void*)ldst, 16, 0, 0);
}
// even/odd group split: float4-group g -> halfbase*(g&1) + (g>>1)*4 + (e&3)
__device__ __forceinline__ int eo2(int e, int hb) {
  const int g = e >> 2;
  return (g & 1) * hb + ((g >> 1) << 2) + (e & 3);
}

// ---------------------------------------------------------------------------
// One block per row (4096 x-rows then 2048 y-rows): min-shift, bf16 round,
// squared norm OF THE ROUNDED VALUES (consistent with the bf16 GEMM).
// Block 0 additionally zeroes all sync state (zero has sign 0 -> parity
// mismatch for it=1, so poison cannot alias a fresh entry).
__global__ __launch_bounds__(256) void prep_kernel(
    const float* __restrict__ x, const float* __restrict__ y,
    unsigned short* __restrict__ xb, unsigned short* __restrict__ yb,
    float* __restrict__ nx, float* __restrict__ ny,
    unsigned* __restrict__ maxCbits, float* __restrict__ out,
    unsigned* __restrict__ uglob, unsigned* __restrict__ vglob,
    unsigned* __restrict__ ublkflag, unsigned* __restrict__ vblkflag,
    unsigned* __restrict__ uroot, unsigned* __restrict__ vroot) {
  const int row = blockIdx.x;
  const int tid = threadIdx.x;

  if (row == 0) {   // merged init (independent of row-0 work below)
    if (tid == 0) { *maxCbits = 0u; out[8388608] = 0.0f; }
    #pragma unroll
    for (int k = 0; k < 16; ++k) uglob[tid + (k << 8)] = 0u;
    #pragma unroll
    for (int k = 0; k < 8; ++k) vglob[tid + (k << 8)] = 0u;
    ublkflag[tid] = 0u;
    vblkflag[tid] = 0u;
    if (tid < 32) { uroot[tid * 32] = 0u; vroot[tid * 32] = 0u; }
  }

  const float* src; unsigned short* dst; float* nd;
  if (row < NROWS) { src = x + (size_t)row * 1024; dst = xb + (size_t)row * 1024; nd = nx + row; }
  else { const int r = row - NROWS; src = y + (size_t)r * 1024; dst = yb + (size_t)r * 1024; nd = ny + r; }

  float4 v = ((const float4*)src)[tid];
  float mn = fminf(fminf(v.x, v.y), fminf(v.z, v.w));
  #pragma unroll
  for (int m = 1; m < 64; m <<= 1) mn = fminf(mn, __shfl_xor(mn, m));
  __shared__ float wred[4];
  const int w = tid >> 6, l = tid & 63;
  if (l == 0) wred[w] = mn;
  __syncthreads();
  mn = fminf(fminf(wred[0], wred[1]), fminf(wred[2], wred[3]));
  __syncthreads();   // wred reused below

  const unsigned short b0 = f2bf(v.x - mn), b1 = f2bf(v.y - mn);
  const unsigned short b2 = f2bf(v.z - mn), b3 = f2bf(v.w - mn);
  ushort4 ub; ub.x = b0; ub.y = b1; ub.z = b2; ub.w = b3;
  ((ushort4*)dst)[tid] = ub;
  const float f0 = bf2f(b0), f1 = bf2f(b1), f2 = bf2f(b2), f3 = bf2f(b3);
  float acc = f0 * f0 + f1 * f1 + f2 * f2 + f3 * f3;
  #pragma unroll
  for (int m = 1; m < 64; m <<= 1) acc += __shfl_xor(acc, m);
  if (l == 0) wred[w] = acc;
  __syncthreads();
  if (tid == 0) *nd = wred[0] + wred[1] + wred[2] + wred[3];
}

// ---------------------------------------------------------------------------
// C[i][j] = max(nx_i + ny_j - 2*dot(xb_i, yb_j), 0).  128x128 block tile,
// BK=64, LDS-staged via global_load_lds (16B), XOR-swizzled (rule #21:
// linear dest + inverse-swz source + swz read). 4 waves as 2x2, each wave
// 64x64 = 4x4 MFMA 16x16x32 tiles x 2 k-chunks per BK.
__global__ __launch_bounds__(256) void cost_gemm_kernel(
    const unsigned short* __restrict__ xb, const unsigned short* __restrict__ yb,
    const float* __restrict__ nx, const float* __restrict__ ny,
    float* __restrict__ C, unsigned* __restrict__ maxCbits) {
  __shared__ __align__(16) unsigned short As[128 * 64];   // 16 KB, [row][64]
  __shared__ __align__(16) unsigned short Bs[128 * 64];   // 16 KB

  const int tid = threadIdx.x;
  const int w = tid >> 6, l = tid & 63;
  const int wr = w >> 1, wc = w & 1;
  const int i0 = blockIdx.y * 128;
  const int j0 = blockIdx.x * 128;
  const int m16 = l & 15, q = l >> 4;

  const int st_row = tid >> 3;          // 0..31 within a call
  const int st_s   = tid & 7;

  floatx4 acc[4][4];
  #pragma unroll
  for (int a = 0; a < 4; ++a)
    #pragma unroll
    for (int b = 0; b < 4; ++b) acc[a][b] = (floatx4){0.f, 0.f, 0.f, 0.f};

  for (int k0 = 0; k0 < 1024; k0 += 64) {
    // ---- stage A and B tiles (4 calls each, 4KB/call)
    #pragma unroll
    for (int c = 0; c < 4; ++c) {
      const int row = c * 32 + st_row;
      const int ss = st_s ^ (row & 7);
      gload_lds16(xb + (size_t)(i0 + row) * 1024 + k0 + ss * 8,
                  &As[c * 2048 + tid * 8]);
    }
    #pragma unroll
    for (int c = 0; c < 4; ++c) {
      const int row = c * 32 + st_row;
      const int ss = st_s ^ (row & 7);
      gload_lds16(yb + (size_t)(j0 + row) * 1024 + k0 + ss * 8,
                  &Bs[c * 2048 + tid * 8]);
    }
    __syncthreads();   // drains vmcnt (gload_lds) + barrier

    // ---- compute: 2 k-chunks x 16 MFMA
    #pragma unroll
    for (int kk = 0; kk < 2; ++kk) {
      short8 av[4], bv[4];
      #pragma unroll
      for (int t = 0; t < 4; ++t) {
        const int row = wr * 64 + t * 16 + m16;
        const int slot = (kk * 4 + q) ^ (row & 7);
        av[t] = *(const short8*)&As[row * 64 + slot * 8];
      }
      #pragma unroll
      for (int t = 0; t < 4; ++t) {
        const int row = wc * 64 + t * 16 + m16;
        const int slot = (kk * 4 + q) ^ (row & 7);
        bv[t] = *(const short8*)&Bs[row * 64 + slot * 8];
      }
      #pragma unroll
      for (int ti = 0; ti < 4; ++ti)
        #pragma unroll
        for (int tj = 0; tj < 4; ++tj)
          acc[ti][tj] = __builtin_amdgcn_mfma_f32_16x16x32_bf16(av[ti], bv[tj], acc[ti][tj], 0, 0, 0);
    }
    __syncthreads();   // before next stage overwrites
  }

  float mx = 0.f;
  #pragma unroll
  for (int ti = 0; ti < 4; ++ti) {
    #pragma unroll
    for (int tj = 0; tj < 4; ++tj) {
      const int i = i0 + wr * 64 + ti * 16 + q * 4;   // C/D: row = quad*4+reg
      const int j = j0 + wc * 64 + tj * 16 + m16;     //       col = lane&15
      const float nyj = ny[j];
      #pragma unroll
      for (int r = 0; r < 4; ++r) {
        float c = nx[i + r] + nyj - 2.0f * acc[ti][tj][r];
        c = fmaxf(c, 0.0f);
        C[(size_t)(i + r) * 2048 + j] = c;
        mx = fmaxf(mx, c);
      }
    }
  }
  __shared__ float mred[4];
  #pragma unroll
  for (int m = 1; m < 64; m <<= 1) mx = fmaxf(mx, __shfl_xor(mx, m));
  if (l == 0) mred[w] = mx;
  __syncthreads();
  if (tid == 0) {
    const float bm = fmaxf(fmaxf(mred[0], mred[1]), fmaxf(mred[2], mred[3]));
    atomicMax(maxCbits, __float_as_uint(bm));
  }
}

// ---------------------------------------------------------------------------
// Persistent dataflow Sinkhorn, 512 threads (8 waves). Block b: rows
// [16b,16b+16) via Ks, columns [8b,8b+8) via KsT. us/vs use the even/odd
// group-split layout (eo2) -> conflict-free float4 reads. Per iteration it
// (parity = it&1): pass1 (wave w: rows 2w,2w+1) -> publish 16 parity u's ->
// raw barrier -> blkflag -> [agg bid0 (tid<256 scan) -> 32 root replicas]
// -> spin -> burst read (8/thread) -> us LDS; pass2 (wave w: col jb+w) ->
// publish 8 v's -> same skeleton -> burst read (4/thread) -> vs LDS.
__global__ __launch_bounds__(512) void sinkhorn_kernel(
    const float* __restrict__ C, const unsigned* __restrict__ maxCbits,
    unsigned* __restrict__ uglob, unsigned* __restrict__ vglob,
    unsigned* __restrict__ ublkflag, unsigned* __restrict__ vblkflag,
    unsigned* __restrict__ uroot, unsigned* __restrict__ vroot,
    float* __restrict__ out) {
  __shared__ __align__(16) unsigned short Ks[16 * 2048];   // 64 KB rows
  __shared__ __align__(16) unsigned short KsT[8 * 4096];   // 64 KB cols
  __shared__ __align__(16) float us[4096];                 // 16 KB (eo2 layout)
  __shared__ __align__(16) float vs[2048];                 // 8 KB (eo2 layout)
  __shared__ __align__(16) float uloc[16];
  __shared__ float dred[8];
  __shared__ unsigned needretry;

  const int tid = threadIdx.x;
  const int bid = blockIdx.x;
  const int w = tid >> 6, l = tid & 63;     // 8 waves
  const int i0 = bid * 16;
  const int jb = bid * 8;

  const float fi = 0.8333333333333334f;   // 0.5/(0.5+0.1)
  const float av = 1.0f / 4096.0f;
  const float bv = 1.0f / 2048.0f;

  // ---- prologue: Ks rows + KsT cols from C (identical exp/round both sides),
  //      v = 1/m. vs is a constant fill and eo2 is bijective on [0,2048) ->
  //      ONE float4 store per thread at vs[4*tid] covers it.
  {
    if (tid == 0) needretry = 0u;
    const float sc = -1.0f / (0.1f * __uint_as_float(*maxCbits));
    for (int il = 0; il < 16; ++il) {      // 512 threads x 4 entries = 2048
      const float* cp = C + (size_t)(i0 + il) * 2048 + tid * 4;
      const float4 c0 = *(const float4*)cp;
      uint2 pk;
      pk.x = (unsigned)f2bf(__expf(c0.x * sc)) | ((unsigned)f2bf(__expf(c0.y * sc)) << 16);
      pk.y = (unsigned)f2bf(__expf(c0.z * sc)) | ((unsigned)f2bf(__expf(c0.w * sc)) << 16);
      *(uint2*)&Ks[il * 2048 + tid * 4] = pk;
    }
    // KsT: column slice C[:, jb..jb+8), strided gather (one-time cost)
    #pragma unroll
    for (int k = 0; k < 8; ++k) {          // 512 threads x 8 rows = 4096
      const int i = tid + (k << 9);
      const float* cp = C + (size_t)i * 2048 + jb;
      const float4 c0 = *(const float4*)cp;
      const float4 c1 = *(const float4*)(cp + 4);
      KsT[0 * 4096 + i] = f2bf(__expf(c0.x * sc));
      KsT[1 * 4096 + i] = f2bf(__expf(c0.y * sc));
      KsT[2 * 4096 + i] = f2bf(__expf(c0.z * sc));
      KsT[3 * 4096 + i] = f2bf(__expf(c0.w * sc));
      KsT[4 * 4096 + i] = f2bf(__expf(c1.x * sc));
      KsT[5 * 4096 + i] = f2bf(__expf(c1.y * sc));
      KsT[6 * 4096 + i] = f2bf(__expf(c1.z * sc));
      KsT[7 * 4096 + i] = f2bf(__expf(c1.w * sc));
    }
    *(float4*)&vs[4 * tid] = make_float4(bv, bv, bv, bv);   // 512 x 4 = 2048
  }
  __syncthreads();

  for (int it = 1; it <= NITER; ++it) {
    const unsigned tagit = (unsigned)it;
    const unsigned par = tagit & 1u;

    // ---- pass 1: wave w rows 2w,2w+1; u = (a/(K v))^fi; publish parity
    float part[2] = {0.f, 0.f};
    const int r0 = w * 2;
    #pragma unroll
    for (int c = 0; c < 4; ++c) {
      const int j0 = c * 512 + l * 8;
      const float4 va = *(const float4*)&vs[eo2(j0, 1024)];       // stride-16B
      const float4 vb = *(const float4*)&vs[eo2(j0 + 4, 1024)];   // stride-16B
      #pragma unroll
      for (int rr = 0; rr < 2; ++rr) {
        const uint4 kb = *(const uint4*)&Ks[(r0 + rr) * 2048 + j0];
        part[rr] += bf2f((unsigned short)kb.x) * va.x + bf2f((unsigned short)(kb.x >> 16)) * va.y
                 +  bf2f((unsigned short)kb.y) * va.z + bf2f((unsigned short)(kb.y >> 16)) * va.w
                 +  bf2f((unsigned short)kb.z) * vb.x + bf2f((unsigned short)(kb.z >> 16)) * vb.y
                 +  bf2f((unsigned short)kb.w) * vb.z + bf2f((unsigned short)(kb.w >> 16)) * vb.w;
      }
    }
    #pragma unroll
    for (int m = 1; m < 64; m <<= 1) {
      part[0] += __shfl_xor(part[0], m);
      part[1] += __shfl_xor(part[1], m);
    }
    if (l == 0) {
      #pragma unroll
      for (int r = 0; r < 2; ++r) {
        const float uv = powfi(av / part[r], fi);
        uloc[r0 + r] = uv;
        astore(&uglob[i0 + r0 + r], packsp(uv, par));
      }
    }
    // Execution-only barrier: all 8 waves have ISSUED their publishes.
    __builtin_amdgcn_s_barrier();
    if (tid == 0) astore(&ublkflag[bid], tagit);
    const unsigned long long udl = __builtin_amdgcn_s_memrealtime() + SPEC_TICKS;

    // ---- fallback gate production: agg bid0 scans flags -> root replicas
    if (bid == 0) {
      if (tid < 256)   // GUARD: only 256 flags exist
        while ((int)(aload(&ublkflag[tid]) - tagit) < 0) __builtin_amdgcn_s_sleep(1);
      __builtin_amdgcn_s_barrier();     // all flags seen (loads only)
      if (tid < 32) astore(&uroot[tid * 32], tagit);
    }

    // ---- spin to deadline, THEN burst read (never read racing the writes)
    while (__builtin_amdgcn_s_memrealtime() < udl) __builtin_amdgcn_s_sleep(1);
    {
      unsigned pend = 0xFFu;
      unsigned gu[8];
      #pragma unroll
      for (int k = 0; k < 8; ++k)
        gu[k] = aload(&uglob[tid + (k << 9)]);
      #pragma unroll
      for (int k = 0; k < 8; ++k)
        if ((gu[k] >> 31) == par) {
          us[eo2(tid + (k << 9), 2048)] = __uint_as_float(gu[k] & 0x7FFFFFFFu);
          pend &= ~(1u << k);
        }
      if (pend) {   // one-shot masked re-read (insurance at tighter SPEC)
        #pragma unroll
        for (int k = 0; k < 8; ++k)
          if (pend & (1u << k))
            gu[k] = aload(&uglob[tid + (k << 9)]);
        #pragma unroll
        for (int k = 0; k < 8; ++k)
          if ((pend & (1u << k)) && (gu[k] >> 31) == par) {
            us[eo2(tid + (k << 9), 2048)] = __uint_as_float(gu[k] & 0x7FFFFFFFu);
            pend &= ~(1u << k);
          }
      }
      if (pend) atomicOr(&needretry, 1u);
      __syncthreads();   // orders us[] writes and needretry (common path: only barrier)
      if (needretry) {   // block-uniform fallback: root-gated retry (rare)
        if (tid == 0)
          while ((int)(aload(&uroot[(bid & 31) * 32]) - tagit) < 0) __builtin_amdgcn_s_sleep(1);
        __syncthreads();
        while (pend) {
          #pragma unroll
          for (int k = 0; k < 8; ++k)
            if (pend & (1u << k))
              gu[k] = aload(&uglob[tid + (k << 9)]);
          #pragma unroll
          for (int k = 0; k < 8; ++k)
            if ((pend & (1u << k)) && (gu[k] >> 31) == par) {
              us[eo2(tid + (k << 9), 2048)] = __uint_as_float(gu[k] & 0x7FFFFFFFu);
              pend &= ~(1u << k);
            }
          if (pend) __builtin_amdgcn_s_sleep(1);
        }
        if (tid == 0) needretry = 0u;
        __syncthreads();   // us[] complete + reset visible
      }
    }

    // ---- pass 2: wave w owns col jb+w; t_j local via KsT
    {
      float t0 = 0.f;
      const int ca = w * 4096;
      #pragma unroll
      for (int c = 0; c < 8; ++c) {
        const int ic = c * 512 + l * 8;
        const float4 ua = *(const float4*)&us[eo2(ic, 2048)];       // stride-16B
        const float4 ub = *(const float4*)&us[eo2(ic + 4, 2048)];   // stride-16B
        const uint4 ka = *(const uint4*)&KsT[ca + ic];
        t0 += bf2f((unsigned short)ka.x) * ua.x + bf2f((unsigned short)(ka.x >> 16)) * ua.y
           +  bf2f((unsigned short)ka.y) * ua.z + bf2f((unsigned short)(ka.y >> 16)) * ua.w
           +  bf2f((unsigned short)ka.z) * ub.x + bf2f((unsigned short)(ka.z >> 16)) * ub.y
           +  bf2f((unsigned short)ka.w) * ub.z + bf2f((unsigned short)(ka.w >> 16)) * ub.w;
      }
      #pragma unroll
      for (int m = 1; m < 64; m <<= 1) t0 += __shfl_xor(t0, m);
      if (l == 0)
        astore(&vglob[jb + w], packsp(powfi(bv / t0, fi), par));
    }
    __builtin_amdgcn_s_barrier();   // execution-only; no drain
    if (tid == 0) astore(&vblkflag[bid], tagit);
    const unsigned long long vdl = __builtin_amdgcn_s_memrealtime() + SPEC_TICKS;

    // ---- fallback gate production: agg bid1 scans flags -> root replicas
    if (bid == 1) {
      if (tid < 256)   // GUARD: only 256 flags exist
        while ((int)(aload(&vblkflag[tid]) - tagit) < 0) __builtin_amdgcn_s_sleep(1);
      __builtin_amdgcn_s_barrier();
      if (tid < 32) astore(&vroot[tid * 32], tagit);
    }

    // ---- spin to deadline, THEN burst read
    while (__builtin_amdgcn_s_memrealtime() < vdl) __builtin_amdgcn_s_sleep(1);
    {
      unsigned pend = 0xFu;
      unsigned gv[4];
      #pragma unroll
      for (int k = 0; k < 4; ++k)
        gv[k] = aload(&vglob[tid + (k << 9)]);
      #pragma unroll
      for (int k = 0; k < 4; ++k)
        if ((gv[k] >> 31) == par) {
          vs[eo2(tid + (k << 9), 1024)] = __uint_as_float(gv[k] & 0x7FFFFFFFu);
          pend &= ~(1u << k);
        }
      if (pend) {   // one-shot masked re-read (insurance)
        #pragma unroll
        for (int k = 0; k < 4; ++k)
          if (pend & (1u << k))
            gv[k] = aload(&vglob[tid + (k << 9)]);
        #pragma unroll
        for (int k = 0; k < 4; ++k)
          if ((pend & (1u << k)) && (gv[k] >> 31) == par) {
            vs[eo2(tid + (k << 9), 1024)] = __uint_as_float(gv[k] & 0x7FFFFFFFu);
            pend &= ~(1u << k);
          }
      }
      if (pend) atomicOr(&needretry, 1u);
      __syncthreads();   // orders vs[] writes and needretry
      if (needretry) {   // block-uniform fallback (rare)
        if (tid == 0)
          while ((int)(aload(&vroot[(bid & 31) * 32]) - tagit) < 0) __builtin_amdgcn_s_sleep(1);
        __syncthreads();
        while (pend) {
          #pragma unroll
          for (int k = 0; k < 4; ++k)
            if (pend & (1u << k))
              gv[k] = aload(&vglob[tid + (k << 9)]);
          #pragma unroll
          for (int k = 0; k < 4; ++k)
            if ((pend & (1u << k)) && (gv[k] >> 31) == par) {
              vs[eo2(tid + (k << 9), 1024)] = __uint_as_float(gv[k] & 0x7FFFFFFFu);
              pend &= ~(1u << k);
            }
          if (pend) __builtin_amdgcn_s_sleep(1);
        }
        if (tid == 0) needretry = 0u;
        __syncthreads();   // vs[] complete + reset visible
      }
    }
  }

  // ---- epilogue: flow.T[j][i0..i0+15] (64B contiguous stores) + dist
  float ur[16];
  *(float4*)&ur[0]  = *(const float4*)&uloc[0];
  *(float4*)&ur[4]  = *(const float4*)&uloc[4];
  *(float4*)&ur[8]  = *(const float4*)&uloc[8];
  *(float4*)&ur[12] = *(const float4*)&uloc[12];
  float distp = 0.f;
  for (int sub = 0; sub < 4; ++sub) {      // 8 waves x 4 subs x 64 = 2048 j
    const int j = w * 256 + sub * 64 + l;
    const float vj = vs[eo2(j, 1024)];
    float o[16];
    #pragma unroll
    for (int il = 0; il < 16; ++il) {
      const float kf = bf2f(Ks[il * 2048 + j]);
      const float fl = ur[il] * kf * vj;
      o[il] = fl;
      distp += C[(size_t)(i0 + il) * 2048 + j] * fl;
    }
    float* op = out + (size_t)j * 4096 + i0;
    *(float4*)(op)      = make_float4(o[0],  o[1],  o[2],  o[3]);
    *(float4*)(op + 4)  = make_float4(o[4],  o[5],  o[6],  o[7]);
    *(float4*)(op + 8)  = make_float4(o[8],  o[9],  o[10], o[11]);
    *(float4*)(op + 12) = make_float4(o[12], o[13], o[14], o[15]);
  }
  #pragma unroll
  for (int m = 1; m < 64; m <<= 1) distp += __shfl_xor(distp, m);
  if (l == 0) dred[w] = distp;
  __syncthreads();
  if (tid == 0) {
    float ds = 0.f;
    #pragma unroll
    for (int k = 0; k < 8; ++k) ds += dred[k];
    unsafeAtomicAdd(out + (size_t)8388608, ds);
  }
}

// ---------------------------------------------------------------------------
extern "C" void kernel_launch(void* const* d_in, const int* in_sizes, int n_in,
                              void* d_out, int out_size, void* d_ws, size_t ws_size,
                              hipStream_t stream) {
  (void)in_sizes; (void)n_in; (void)out_size; (void)ws_size;
  const float* x = (const float*)d_in[0];
  const float* y = (const float*)d_in[1];
  float* out = (float*)d_out;
  char* ws = (char*)d_ws;

  // workspace layout (bytes)
  float*              Cmat     = (float*)(ws + 0);                 // 32 MB
  unsigned short*     xb       = (unsigned short*)(ws + 33554432); // 8 MB
  unsigned short*     yb       = (unsigned short*)(ws + 41943040); // 4 MB
  float*              nx       = (float*)(ws + 46137344);          // 16 KB
  float*              ny       = (float*)(ws + 46153728);          // 8 KB
  unsigned*           maxC     = (unsigned*)(ws + 46161920);
  unsigned*           uglob    = (unsigned*)(ws + 46162432);       // 16 KB (4B/entry)
  unsigned*           vglob    = (unsigned*)(ws + 46178816);       // 8 KB (4B/entry)
  unsigned*           ublkflag = (unsigned*)(ws + 46187008);       // 256 u32
  unsigned*           vblkflag = (unsigned*)(ws + 46188032);       // 256 u32
  unsigned*           uroot    = (unsigned*)(ws + 46189056);       // 32 x 128B
  unsigned*           vroot    = (unsigned*)(ws + 46193152);       // 32 x 128B

  hipLaunchKernelGGL(prep_kernel, dim3(6144), dim3(256), 0, stream, x, y, xb, yb, nx, ny,
                     maxC, out, uglob, vglob, ublkflag, vblkflag, uroot, vroot);
  hipLaunchKernelGGL(cost_gemm_kernel, dim3(16, 32), dim3(256), 0, stream, xb, yb, nx, ny, Cmat, maxC);
  hipLaunchKernelGGL(sinkhorn_kernel, dim3(NBLK), dim3(512), 0, stream,
                     Cmat, maxC, uglob, vglob, ublkflag, vblkflag, uroot, vroot, out);
}

// Round 18
// 605.543 us; speedup vs baseline: 1.0451x; 1.0451x over previous
//
#include <hip/hip_runtime.h>

// ---------------------------------------------------------------------------
// OT_Attn: unbalanced Sinkhorn on MI355X.
// R23: REVERT to R21 (SPEC_TICKS=70), executing R22's pre-committed
// falsifier action. Visibility bisection COMPLETE: 60 fails hard (R12),
// 65 marginal (R22: +20us, masked re-read engages every exchange, VALUBusy
// down), 70 clean (R21: sinkhorn 517.5us, zero fallback signature). The
// fleet-wide store-visibility constant is pinned to (0.65, 0.70] us.
// This configuration is the measured floor of the timed-speculative sync
// structure: per iter = 2x0.70us spins (hardware constant) + ~1.7us compute
// (8 waves optimal; 16 regressed R17) + ~1.0us burst reads (line-minimized
// via sign-parity 4B entries, R14) + ~0.6us barriers/publish.
// Ladder: 862 (R5 baseline) -> 806 (R8 drain cut) -> 727 (R9 timed spec) ->
// 686 (R10 SPEC=85) -> 630 (R14 4B entries) -> 550 (R15 512 thr) -> 547+
// gemm LDS (R16) -> 538.5 (R19 eo2 layout) -> 531 (R20 SPEC=78) ->
// 517.5 (R21 SPEC=70). Total 862 -> ~613 us.
// Skeleton: publish sign-parity 4B entries -> raw barrier -> blkflag ->
// [agg bid0/1 scans 256 flags -> 32 line-spaced root replicas] -> spin to
// deadline -> burst read -> one-shot masked re-read -> (rare) root-gated
// retry. Never read during the publish window (R11).
// ONLY validated relaxed AGENT __hip_atomic ops touch shared sync state.
// ---------------------------------------------------------------------------

#define NROWS 4096
#define MCOLS 2048
#define NITER 100
#define NBLK  256    // 1 block/CU (LDS-bound), grid == CU count -> co-resident
#define SPEC_TICKS 70ull   // 0.70 us at 100 MHz realtime clock (measured floor)

using short8  = __attribute__((ext_vector_type(8))) short;
using floatx4 = __attribute__((ext_vector_type(4))) float;

__device__ __forceinline__ float bf2f(unsigned short u) {
  return __uint_as_float(((unsigned)u) << 16);
}
__device__ __forceinline__ unsigned short f2bf(float f) {  // RNE
  unsigned u = __float_as_uint(f);
  u += 0x7fffu + ((u >> 16) & 1u);
  return (unsigned short)(u >> 16);
}
__device__ __forceinline__ float powfi(float x, float fi) {
  return __expf(fi * __logf(x));
}
// sign-bit-parity pack: val > 0 strictly -> sign bit is free
__device__ __forceinline__ unsigned packsp(float v, unsigned parity) {
  return __float_as_uint(v) | (parity << 31);
}
__device__ __forceinline__ unsigned aload(const unsigned* p) {
  return __hip_atomic_load(p, __ATOMIC_RELAXED, __HIP_MEMORY_SCOPE_AGENT);
}
__device__ __forceinline__ void astore(unsigned* p, unsigned v) {
  __hip_atomic_store(p, v, __ATOMIC_RELAXED, __HIP_MEMORY_SCOPE_AGENT);
}
// async global->LDS, 16B per lane (dest = wave-uniform base + lane*16)
__device__ __forceinline__ void gload_lds16(const unsigned short* gsrc, unsigned short* ldst) {
  __builtin_amdgcn_global_load_lds(
      (const __attribute__((address_space(1))) void*)gsrc,
      (__attribute__((address_space(3))) void*)ldst, 16, 0, 0);
}
// even/odd group split: float4-group g -> halfbase*(g&1) + (g>>1)*4 + (e&3)
__device__ __forceinline__ int eo2(int e, int hb) {
  const int g = e >> 2;
  return (g & 1) * hb + ((g >> 1) << 2) + (e & 3);
}

// ---------------------------------------------------------------------------
// One block per row (4096 x-rows then 2048 y-rows): min-shift, bf16 round,
// squared norm OF THE ROUNDED VALUES (consistent with the bf16 GEMM).
// Block 0 additionally zeroes all sync state (zero has sign 0 -> parity
// mismatch for it=1, so poison cannot alias a fresh entry).
__global__ __launch_bounds__(256) void prep_kernel(
    const float* __restrict__ x, const float* __restrict__ y,
    unsigned short* __restrict__ xb, unsigned short* __restrict__ yb,
    float* __restrict__ nx, float* __restrict__ ny,
    unsigned* __restrict__ maxCbits, float* __restrict__ out,
    unsigned* __restrict__ uglob, unsigned* __restrict__ vglob,
    unsigned* __restrict__ ublkflag, unsigned* __restrict__ vblkflag,
    unsigned* __restrict__ uroot, unsigned* __restrict__ vroot) {
  const int row = blockIdx.x;
  const int tid = threadIdx.x;

  if (row == 0) {   // merged init (independent of row-0 work below)
    if (tid == 0) { *maxCbits = 0u; out[8388608] = 0.0f; }
    #pragma unroll
    for (int k = 0; k < 16; ++k) uglob[tid + (k << 8)] = 0u;
    #pragma unroll
    for (int k = 0; k < 8; ++k) vglob[tid + (k << 8)] = 0u;
    ublkflag[tid] = 0u;
    vblkflag[tid] = 0u;
    if (tid < 32) { uroot[tid * 32] = 0u; vroot[tid * 32] = 0u; }
  }

  const float* src; unsigned short* dst; float* nd;
  if (row < NROWS) { src = x + (size_t)row * 1024; dst = xb + (size_t)row * 1024; nd = nx + row; }
  else { const int r = row - NROWS; src = y + (size_t)r * 1024; dst = yb + (size_t)r * 1024; nd = ny + r; }

  float4 v = ((const float4*)src)[tid];
  float mn = fminf(fminf(v.x, v.y), fminf(v.z, v.w));
  #pragma unroll
  for (int m = 1; m < 64; m <<= 1) mn = fminf(mn, __shfl_xor(mn, m));
  __shared__ float wred[4];
  const int w = tid >> 6, l = tid & 63;
  if (l == 0) wred[w] = mn;
  __syncthreads();
  mn = fminf(fminf(wred[0], wred[1]), fminf(wred[2], wred[3]));
  __syncthreads();   // wred reused below

  const unsigned short b0 = f2bf(v.x - mn), b1 = f2bf(v.y - mn);
  const unsigned short b2 = f2bf(v.z - mn), b3 = f2bf(v.w - mn);
  ushort4 ub; ub.x = b0; ub.y = b1; ub.z = b2; ub.w = b3;
  ((ushort4*)dst)[tid] = ub;
  const float f0 = bf2f(b0), f1 = bf2f(b1), f2 = bf2f(b2), f3 = bf2f(b3);
  float acc = f0 * f0 + f1 * f1 + f2 * f2 + f3 * f3;
  #pragma unroll
  for (int m = 1; m < 64; m <<= 1) acc += __shfl_xor(acc, m);
  if (l == 0) wred[w] = acc;
  __syncthreads();
  if (tid == 0) *nd = wred[0] + wred[1] + wred[2] + wred[3];
}

// ---------------------------------------------------------------------------
// C[i][j] = max(nx_i + ny_j - 2*dot(xb_i, yb_j), 0).  128x128 block tile,
// BK=64, LDS-staged via global_load_lds (16B), XOR-swizzled (rule #21:
// linear dest + inverse-swz source + swz read). 4 waves as 2x2, each wave
// 64x64 = 4x4 MFMA 16x16x32 tiles x 2 k-chunks per BK.
__global__ __launch_bounds__(256) void cost_gemm_kernel(
    const unsigned short* __restrict__ xb, const unsigned short* __restrict__ yb,
    const float* __restrict__ nx, const float* __restrict__ ny,
    float* __restrict__ C, unsigned* __restrict__ maxCbits) {
  __shared__ __align__(16) unsigned short As[128 * 64];   // 16 KB, [row][64]
  __shared__ __align__(16) unsigned short Bs[128 * 64];   // 16 KB

  const int tid = threadIdx.x;
  const int w = tid >> 6, l = tid & 63;
  const int wr = w >> 1, wc = w & 1;
  const int i0 = blockIdx.y * 128;
  const int j0 = blockIdx.x * 128;
  const int m16 = l & 15, q = l >> 4;

  const int st_row = tid >> 3;          // 0..31 within a call
  const int st_s   = tid & 7;

  floatx4 acc[4][4];
  #pragma unroll
  for (int a = 0; a < 4; ++a)
    #pragma unroll
    for (int b = 0; b < 4; ++b) acc[a][b] = (floatx4){0.f, 0.f, 0.f, 0.f};

  for (int k0 = 0; k0 < 1024; k0 += 64) {
    // ---- stage A and B tiles (4 calls each, 4KB/call)
    #pragma unroll
    for (int c = 0; c < 4; ++c) {
      const int row = c * 32 + st_row;
      const int ss = st_s ^ (row & 7);
      gload_lds16(xb + (size_t)(i0 + row) * 1024 + k0 + ss * 8,
                  &As[c * 2048 + tid * 8]);
    }
    #pragma unroll
    for (int c = 0; c < 4; ++c) {
      const int row = c * 32 + st_row;
      const int ss = st_s ^ (row & 7);
      gload_lds16(yb + (size_t)(j0 + row) * 1024 + k0 + ss * 8,
                  &Bs[c * 2048 + tid * 8]);
    }
    __syncthreads();   // drains vmcnt (gload_lds) + barrier

    // ---- compute: 2 k-chunks x 16 MFMA
    #pragma unroll
    for (int kk = 0; kk < 2; ++kk) {
      short8 av[4], bv[4];
      #pragma unroll
      for (int t = 0; t < 4; ++t) {
        const int row = wr * 64 + t * 16 + m16;
        const int slot = (kk * 4 + q) ^ (row & 7);
        av[t] = *(const short8*)&As[row * 64 + slot * 8];
      }
      #pragma unroll
      for (int t = 0; t < 4; ++t) {
        const int row = wc * 64 + t * 16 + m16;
        const int slot = (kk * 4 + q) ^ (row & 7);
        bv[t] = *(const short8*)&Bs[row * 64 + slot * 8];
      }
      #pragma unroll
      for (int ti = 0; ti < 4; ++ti)
        #pragma unroll
        for (int tj = 0; tj < 4; ++tj)
          acc[ti][tj] = __builtin_amdgcn_mfma_f32_16x16x32_bf16(av[ti], bv[tj], acc[ti][tj], 0, 0, 0);
    }
    __syncthreads();   // before next stage overwrites
  }

  float mx = 0.f;
  #pragma unroll
  for (int ti = 0; ti < 4; ++ti) {
    #pragma unroll
    for (int tj = 0; tj < 4; ++tj) {
      const int i = i0 + wr * 64 + ti * 16 + q * 4;   // C/D: row = quad*4+reg
      const int j = j0 + wc * 64 + tj * 16 + m16;     //       col = lane&15
      const float nyj = ny[j];
      #pragma unroll
      for (int r = 0; r < 4; ++r) {
        float c = nx[i + r] + nyj - 2.0f * acc[ti][tj][r];
        c = fmaxf(c, 0.0f);
        C[(size_t)(i + r) * 2048 + j] = c;
        mx = fmaxf(mx, c);
      }
    }
  }
  __shared__ float mred[4];
  #pragma unroll
  for (int m = 1; m < 64; m <<= 1) mx = fmaxf(mx, __shfl_xor(mx, m));
  if (l == 0) mred[w] = mx;
  __syncthreads();
  if (tid == 0) {
    const float bm = fmaxf(fmaxf(mred[0], mred[1]), fmaxf(mred[2], mred[3]));
    atomicMax(maxCbits, __float_as_uint(bm));
  }
}

// ---------------------------------------------------------------------------
// Persistent dataflow Sinkhorn, 512 threads (8 waves). Block b: rows
// [16b,16b+16) via Ks, columns [8b,8b+8) via KsT. us/vs use the even/odd
// group-split layout (eo2) -> conflict-free float4 reads. Per iteration it
// (parity = it&1): pass1 (wave w: rows 2w,2w+1) -> publish 16 parity u's ->
// raw barrier -> blkflag -> [agg bid0 (tid<256 scan) -> 32 root replicas]
// -> spin -> burst read (8/thread) -> us LDS; pass2 (wave w: col jb+w) ->
// publish 8 v's -> same skeleton -> burst read (4/thread) -> vs LDS.
__global__ __launch_bounds__(512) void sinkhorn_kernel(
    const float* __restrict__ C, const unsigned* __restrict__ maxCbits,
    unsigned* __restrict__ uglob, unsigned* __restrict__ vglob,
    unsigned* __restrict__ ublkflag, unsigned* __restrict__ vblkflag,
    unsigned* __restrict__ uroot, unsigned* __restrict__ vroot,
    float* __restrict__ out) {
  __shared__ __align__(16) unsigned short Ks[16 * 2048];   // 64 KB rows
  __shared__ __align__(16) unsigned short KsT[8 * 4096];   // 64 KB cols
  __shared__ __align__(16) float us[4096];                 // 16 KB (eo2 layout)
  __shared__ __align__(16) float vs[2048];                 // 8 KB (eo2 layout)
  __shared__ __align__(16) float uloc[16];
  __shared__ float dred[8];
  __shared__ unsigned needretry;

  const int tid = threadIdx.x;
  const int bid = blockIdx.x;
  const int w = tid >> 6, l = tid & 63;     // 8 waves
  const int i0 = bid * 16;
  const int jb = bid * 8;

  const float fi = 0.8333333333333334f;   // 0.5/(0.5+0.1)
  const float av = 1.0f / 4096.0f;
  const float bv = 1.0f / 2048.0f;

  // ---- prologue: Ks rows + KsT cols from C (identical exp/round both sides),
  //      v = 1/m. vs is a constant fill and eo2 is bijective on [0,2048) ->
  //      ONE float4 store per thread at vs[4*tid] covers it.
  {
    if (tid == 0) needretry = 0u;
    const float sc = -1.0f / (0.1f * __uint_as_float(*maxCbits));
    for (int il = 0; il < 16; ++il) {      // 512 threads x 4 entries = 2048
      const float* cp = C + (size_t)(i0 + il) * 2048 + tid * 4;
      const float4 c0 = *(const float4*)cp;
      uint2 pk;
      pk.x = (unsigned)f2bf(__expf(c0.x * sc)) | ((unsigned)f2bf(__expf(c0.y * sc)) << 16);
      pk.y = (unsigned)f2bf(__expf(c0.z * sc)) | ((unsigned)f2bf(__expf(c0.w * sc)) << 16);
      *(uint2*)&Ks[il * 2048 + tid * 4] = pk;
    }
    // KsT: column slice C[:, jb..jb+8), strided gather (one-time cost)
    #pragma unroll
    for (int k = 0; k < 8; ++k) {          // 512 threads x 8 rows = 4096
      const int i = tid + (k << 9);
      const float* cp = C + (size_t)i * 2048 + jb;
      const float4 c0 = *(const float4*)cp;
      const float4 c1 = *(const float4*)(cp + 4);
      KsT[0 * 4096 + i] = f2bf(__expf(c0.x * sc));
      KsT[1 * 4096 + i] = f2bf(__expf(c0.y * sc));
      KsT[2 * 4096 + i] = f2bf(__expf(c0.z * sc));
      KsT[3 * 4096 + i] = f2bf(__expf(c0.w * sc));
      KsT[4 * 4096 + i] = f2bf(__expf(c1.x * sc));
      KsT[5 * 4096 + i] = f2bf(__expf(c1.y * sc));
      KsT[6 * 4096 + i] = f2bf(__expf(c1.z * sc));
      KsT[7 * 4096 + i] = f2bf(__expf(c1.w * sc));
    }
    *(float4*)&vs[4 * tid] = make_float4(bv, bv, bv, bv);   // 512 x 4 = 2048
  }
  __syncthreads();

  for (int it = 1; it <= NITER; ++it) {
    const unsigned tagit = (unsigned)it;
    const unsigned par = tagit & 1u;

    // ---- pass 1: wave w rows 2w,2w+1; u = (a/(K v))^fi; publish parity
    float part[2] = {0.f, 0.f};
    const int r0 = w * 2;
    #pragma unroll
    for (int c = 0; c < 4; ++c) {
      const int j0 = c * 512 + l * 8;
      const float4 va = *(const float4*)&vs[eo2(j0, 1024)];       // stride-16B
      const float4 vb = *(const float4*)&vs[eo2(j0 + 4, 1024)];   // stride-16B
      #pragma unroll
      for (int rr = 0; rr < 2; ++rr) {
        const uint4 kb = *(const uint4*)&Ks[(r0 + rr) * 2048 + j0];
        part[rr] += bf2f((unsigned short)kb.x) * va.x + bf2f((unsigned short)(kb.x >> 16)) * va.y
                 +  bf2f((unsigned short)kb.y) * va.z + bf2f((unsigned short)(kb.y >> 16)) * va.w
                 +  bf2f((unsigned short)kb.z) * vb.x + bf2f((unsigned short)(kb.z >> 16)) * vb.y
                 +  bf2f((unsigned short)kb.w) * vb.z + bf2f((unsigned short)(kb.w >> 16)) * vb.w;
      }
    }
    #pragma unroll
    for (int m = 1; m < 64; m <<= 1) {
      part[0] += __shfl_xor(part[0], m);
      part[1] += __shfl_xor(part[1], m);
    }
    if (l == 0) {
      #pragma unroll
      for (int r = 0; r < 2; ++r) {
        const float uv = powfi(av / part[r], fi);
        uloc[r0 + r] = uv;
        astore(&uglob[i0 + r0 + r], packsp(uv, par));
      }
    }
    // Execution-only barrier: all 8 waves have ISSUED their publishes.
    __builtin_amdgcn_s_barrier();
    if (tid == 0) astore(&ublkflag[bid], tagit);
    const unsigned long long udl = __builtin_amdgcn_s_memrealtime() + SPEC_TICKS;

    // ---- fallback gate production: agg bid0 scans flags -> root replicas
    if (bid == 0) {
      if (tid < 256)   // GUARD: only 256 flags exist
        while ((int)(aload(&ublkflag[tid]) - tagit) < 0) __builtin_amdgcn_s_sleep(1);
      __builtin_amdgcn_s_barrier();     // all flags seen (loads only)
      if (tid < 32) astore(&uroot[tid * 32], tagit);
    }

    // ---- spin to deadline, THEN burst read (never read racing the writes)
    while (__builtin_amdgcn_s_memrealtime() < udl) __builtin_amdgcn_s_sleep(1);
    {
      unsigned pend = 0xFFu;
      unsigned gu[8];
      #pragma unroll
      for (int k = 0; k < 8; ++k)
        gu[k] = aload(&uglob[tid + (k << 9)]);
      #pragma unroll
      for (int k = 0; k < 8; ++k)
        if ((gu[k] >> 31) == par) {
          us[eo2(tid + (k << 9), 2048)] = __uint_as_float(gu[k] & 0x7FFFFFFFu);
          pend &= ~(1u << k);
        }
      if (pend) {   // one-shot masked re-read (dormant at SPEC=70)
        #pragma unroll
        for (int k = 0; k < 8; ++k)
          if (pend & (1u << k))
            gu[k] = aload(&uglob[tid + (k << 9)]);
        #pragma unroll
        for (int k = 0; k < 8; ++k)
          if ((pend & (1u << k)) && (gu[k] >> 31) == par) {
            us[eo2(tid + (k << 9), 2048)] = __uint_as_float(gu[k] & 0x7FFFFFFFu);
            pend &= ~(1u << k);
          }
      }
      if (pend) atomicOr(&needretry, 1u);
      __syncthreads();   // orders us[] writes and needretry (common path: only barrier)
      if (needretry) {   // block-uniform fallback: root-gated retry (rare)
        if (tid == 0)
          while ((int)(aload(&uroot[(bid & 31) * 32]) - tagit) < 0) __builtin_amdgcn_s_sleep(1);
        __syncthreads();
        while (pend) {
          #pragma unroll
          for (int k = 0; k < 8; ++k)
            if (pend & (1u << k))
              gu[k] = aload(&uglob[tid + (k << 9)]);
          #pragma unroll
          for (int k = 0; k < 8; ++k)
            if ((pend & (1u << k)) && (gu[k] >> 31) == par) {
              us[eo2(tid + (k << 9), 2048)] = __uint_as_float(gu[k] & 0x7FFFFFFFu);
              pend &= ~(1u << k);
            }
          if (pend) __builtin_amdgcn_s_sleep(1);
        }
        if (tid == 0) needretry = 0u;
        __syncthreads();   // us[] complete + reset visible
      }
    }

    // ---- pass 2: wave w owns col jb+w; t_j local via KsT
    {
      float t0 = 0.f;
      const int ca = w * 4096;
      #pragma unroll
      for (int c = 0; c < 8; ++c) {
        const int ic = c * 512 + l * 8;
        const float4 ua = *(const float4*)&us[eo2(ic, 2048)];       // stride-16B
        const float4 ub = *(const float4*)&us[eo2(ic + 4, 2048)];   // stride-16B
        const uint4 ka = *(const uint4*)&KsT[ca + ic];
        t0 += bf2f((unsigned short)ka.x) * ua.x + bf2f((unsigned short)(ka.x >> 16)) * ua.y
           +  bf2f((unsigned short)ka.y) * ua.z + bf2f((unsigned short)(ka.y >> 16)) * ua.w
           +  bf2f((unsigned short)ka.z) * ub.x + bf2f((unsigned short)(ka.z >> 16)) * ub.y
           +  bf2f((unsigned short)ka.w) * ub.z + bf2f((unsigned short)(ka.w >> 16)) * ub.w;
      }
      #pragma unroll
      for (int m = 1; m < 64; m <<= 1) t0 += __shfl_xor(t0, m);
      if (l == 0)
        astore(&vglob[jb + w], packsp(powfi(bv / t0, fi), par));
    }
    __builtin_amdgcn_s_barrier();   // execution-only; no drain
    if (tid == 0) astore(&vblkflag[bid], tagit);
    const unsigned long long vdl = __builtin_amdgcn_s_memrealtime() + SPEC_TICKS;

    // ---- fallback gate production: agg bid1 scans flags -> root replicas
    if (bid == 1) {
      if (tid < 256)   // GUARD: only 256 flags exist
        while ((int)(aload(&vblkflag[tid]) - tagit) < 0) __builtin_amdgcn_s_sleep(1);
      __builtin_amdgcn_s_barrier();
      if (tid < 32) astore(&vroot[tid * 32], tagit);
    }

    // ---- spin to deadline, THEN burst read
    while (__builtin_amdgcn_s_memrealtime() < vdl) __builtin_amdgcn_s_sleep(1);
    {
      unsigned pend = 0xFu;
      unsigned gv[4];
      #pragma unroll
      for (int k = 0; k < 4; ++k)
        gv[k] = aload(&vglob[tid + (k << 9)]);
      #pragma unroll
      for (int k = 0; k < 4; ++k)
        if ((gv[k] >> 31) == par) {
          vs[eo2(tid + (k << 9), 1024)] = __uint_as_float(gv[k] & 0x7FFFFFFFu);
          pend &= ~(1u << k);
        }
      if (pend) {   // one-shot masked re-read (dormant)
        #pragma unroll
        for (int k = 0; k < 4; ++k)
          if (pend & (1u << k))
            gv[k] = aload(&vglob[tid + (k << 9)]);
        #pragma unroll
        for (int k = 0; k < 4; ++k)
          if ((pend & (1u << k)) && (gv[k] >> 31) == par) {
            vs[eo2(tid + (k << 9), 1024)] = __uint_as_float(gv[k] & 0x7FFFFFFFu);
            pend &= ~(1u << k);
          }
      }
      if (pend) atomicOr(&needretry, 1u);
      __syncthreads();   // orders vs[] writes and needretry
      if (needretry) {   // block-uniform fallback (rare)
        if (tid == 0)
          while ((int)(aload(&vroot[(bid & 31) * 32]) - tagit) < 0) __builtin_amdgcn_s_sleep(1);
        __syncthreads();
        while (pend) {
          #pragma unroll
          for (int k = 0; k < 4; ++k)
            if (pend & (1u << k))
              gv[k] = aload(&vglob[tid + (k << 9)]);
          #pragma unroll
          for (int k = 0; k < 4; ++k)
            if ((pend & (1u << k)) && (gv[k] >> 31) == par) {
              vs[eo2(tid + (k << 9), 1024)] = __uint_as_float(gv[k] & 0x7FFFFFFFu);
              pend &= ~(1u << k);
            }
          if (pend) __builtin_amdgcn_s_sleep(1);
        }
        if (tid == 0) needretry = 0u;
        __syncthreads();   // vs[] complete + reset visible
      }
    }
  }

  // ---- epilogue: flow.T[j][i0..i0+15] (64B contiguous stores) + dist
  float ur[16];
  *(float4*)&ur[0]  = *(const float4*)&uloc[0];
  *(float4*)&ur[4]  = *(const float4*)&uloc[4];
  *(float4*)&ur[8]  = *(const float4*)&uloc[8];
  *(float4*)&ur[12] = *(const float4*)&uloc[12];
  float distp = 0.f;
  for (int sub = 0; sub < 4; ++sub) {      // 8 waves x 4 subs x 64 = 2048 j
    const int j = w * 256 + sub * 64 + l;
    const float vj = vs[eo2(j, 1024)];
    float o[16];
    #pragma unroll
    for (int il = 0; il < 16; ++il) {
      const float kf = bf2f(Ks[il * 2048 + j]);
      const float fl = ur[il] * kf * vj;
      o[il] = fl;
      distp += C[(size_t)(i0 + il) * 2048 + j] * fl;
    }
    float* op = out + (size_t)j * 4096 + i0;
    *(float4*)(op)      = make_float4(o[0],  o[1],  o[2],  o[3]);
    *(float4*)(op + 4)  = make_float4(o[4],  o[5],  o[6],  o[7]);
    *(float4*)(op + 8)  = make_float4(o[8],  o[9],  o[10], o[11]);
    *(float4*)(op + 12) = make_float4(o[12], o[13], o[14], o[15]);
  }
  #pragma unroll
  for (int m = 1; m < 64; m <<= 1) distp += __shfl_xor(distp, m);
  if (l == 0) dred[w] = distp;
  __syncthreads();
  if (tid == 0) {
    float ds = 0.f;
    #pragma unroll
    for (int k = 0; k < 8; ++k) ds += dred[k];
    unsafeAtomicAdd(out + (size_t)8388608, ds);
  }
}

// ---------------------------------------------------------------------------
extern "C" void kernel_launch(void* const* d_in, const int* in_sizes, int n_in,
                              void* d_out, int out_size, void* d_ws, size_t ws_size,
                              hipStream_t stream) {
  (void)in_sizes; (void)n_in; (void)out_size; (void)ws_size;
  const float* x = (const float*)d_in[0];
  const float* y = (const float*)d_in[1];
  float* out = (float*)d_out;
  char* ws = (char*)d_ws;

  // workspace layout (bytes)
  float*              Cmat     = (float*)(ws + 0);                 // 32 MB
  unsigned short*     xb       = (unsigned short*)(ws + 33554432); // 8 MB
  unsigned short*     yb       = (unsigned short*)(ws + 41943040); // 4 MB
  float*              nx       = (float*)(ws + 46137344);          // 16 KB
  float*              ny       = (float*)(ws + 46153728);          // 8 KB
  unsigned*           maxC     = (unsigned*)(ws + 46161920);
  unsigned*           uglob    = (unsigned*)(ws + 46162432);       // 16 KB (4B/entry)
  unsigned*           vglob    = (unsigned*)(ws + 46178816);       // 8 KB (4B/entry)
  unsigned*           ublkflag = (unsigned*)(ws + 46187008);       // 256 u32
  unsigned*           vblkflag = (unsigned*)(ws + 46188032);       // 256 u32
  unsigned*           uroot    = (unsigned*)(ws + 46189056);       // 32 x 128B
  unsigned*           vroot    = (unsigned*)(ws + 46193152);       // 32 x 128B

  hipLaunchKernelGGL(prep_kernel, dim3(6144), dim3(256), 0, stream, x, y, xb, yb, nx, ny,
                     maxC, out, uglob, vglob, ublkflag, vblkflag, uroot, vroot);
  hipLaunchKernelGGL(cost_gemm_kernel, dim3(16, 32), dim3(256), 0, stream, xb, yb, nx, ny, Cmat, maxC);
  hipLaunchKernelGGL(sinkhorn_kernel, dim3(NBLK), dim3(512), 0, stream,
                     Cmat, maxC, uglob, vglob, ublkflag, vblkflag, uroot, vroot, out);
}